// Round 18
// baseline (282.908 us; speedup 1.0000x reference)
//
#include <hip/hip_runtime.h>
#include <cstdint>
#include <cstddef>

#define NC 64
#define LN2 0.6931471805599453f

typedef _Float16 halfx4 __attribute__((ext_vector_type(4)));
typedef float floatx4 __attribute__((ext_vector_type(4)));

#define MFMA16(a, b, c) __builtin_amdgcn_mfma_f32_16x16x16f16((a), (b), (c), 0, 0, 0)

template <int CTRL>
static __device__ __forceinline__ float dppf(float x) {
    return __int_as_float(__builtin_amdgcn_update_dpp(
        0, __float_as_int(x), CTRL, 0xf, 0xf, true));
}
static __device__ __forceinline__ float wave_sum_bcast(float x) {
    x = x + dppf<0x111>(x);
    x = x + dppf<0x112>(x);
    x = x + dppf<0x114>(x);
    x = x + dppf<0x118>(x);
    x = x + dppf<0x142>(x);   // row_bcast15
    x = x + dppf<0x143>(x);   // row_bcast31
    return __int_as_float(__builtin_amdgcn_readlane(__float_as_int(x), 63));
}

// ---------- kernel 1: length-rank permutation + gold scores ----------
__global__ __launch_bounds__(64, 1)
void prep_kernel(const float* __restrict__ logits, const float* __restrict__ trans,
                 const float* __restrict__ inita, const int* __restrict__ lens,
                 const int* __restrict__ tags, int* __restrict__ perm,
                 float* __restrict__ gold, int N, int T)
{
    const int b = blockIdx.x;
    const int lane = threadIdx.x;
    const int lb = lens[b];

    int cnt = 0;
    for (int j = lane; j < N; j += 64) {
        int lj = lens[j];
        cnt += (lj < lb || (lj == lb && j < b)) ? 1 : 0;
    }
    float cf = wave_sum_bcast((float)cnt);

    const float* lg = logits + (size_t)b * T * NC;
    const int* tg = tags + (size_t)b * T;
    float g = 0.f;
    for (int t = 1 + lane; t < lb; t += 64) {
        int cur = tg[t], prv = tg[t - 1];
        g += trans[cur * NC + prv] + lg[t * NC + cur];
    }
    g = wave_sum_bcast(g);

    if (lane == 0) {
        int t0 = tg[0];
        gold[b] = inita[t0] + lg[t0] + g;
        perm[(int)(cf + 0.5f)] = b;
    }
}

// ---------- kernel 2: batched MFMA forward/backward CRF ----------
__global__ __launch_bounds__(128, 1)
void crf_mfma(const float* __restrict__ logits, const float* __restrict__ trans,
              const float* __restrict__ inita, const int* __restrict__ lens,
              const int* __restrict__ perm, const float* __restrict__ gold,
              float* __restrict__ out, int N, int T)
{
    const int g = blockIdx.x;          // 32 groups of 16 sequences
    const int tid = threadIdx.x;
    const int wid = tid >> 6;          // wave 0 = forward, wave 1 = backward
    const int lane = tid & 63;
    const int q = lane >> 4;           // class sub-block
    const int col = lane & 15;         // sequence slot within group

    __shared__ float Xf[64][16], Xb[64][16];
    __shared__ float Lshf[16], Lshb[16];

    const int sid = perm[16 * g + col];
    const int mylen = lens[sid];
    const int mym = (mylen - 1) >> 1;
    const float* lgb = logits + (size_t)sid * T * NC;

    // group bounds (uniform per block)
    int maxm = 0, maxlen = 2, minm = 1 << 30;
    for (int c = 0; c < 16; ++c) {
        int s2 = perm[16 * g + c];
        int ll = lens[s2];
        int mm = (ll - 1) >> 1;
        maxm = mm > maxm ? mm : maxm;
        maxlen = ll > maxlen ? ll : maxlen;
        minm = mm < minm ? mm : minm;
    }

    const floatx4 zf = {0.f, 0.f, 0.f, 0.f};

    // ---- probe A orientation (verified round 17)
    halfx4 Ao;
    Ao[0] = (_Float16)1.f; Ao[1] = (_Float16)1.f;
    Ao[2] = (_Float16)1.f; Ao[3] = (_Float16)1.f;
    int flip;
    {
        halfx4 ap;
        float pv = (float)(1 << col);
        ap[0] = (_Float16)pv; ap[1] = (_Float16)pv;
        ap[2] = (_Float16)pv; ap[3] = (_Float16)pv;
        floatx4 dp = MFMA16(ap, Ao, zf);
        flip = __builtin_amdgcn_readfirstlane(dp[0] > 1000.f ? 1 : 0);
    }
    const bool useT = ((wid == 1) ? 1 : 0) ^ flip;

    // ---- resident E fragments
    halfx4 Afr[4][4];
    #pragma unroll
    for (int mt = 0; mt < 4; ++mt)
        #pragma unroll
        for (int kt = 0; kt < 4; ++kt) {
            halfx4 av;
            #pragma unroll
            for (int i = 0; i < 4; ++i) {
                int m = 16 * mt + col;
                int k = 16 * kt + 4 * q + i;
                float tv = useT ? trans[k * NC + m] : trans[m * NC + k];
                av[i] = (_Float16)__expf(tv);
            }
            Afr[mt][kt] = av;
        }

    // ---- state
    floatx4 U[4];
    halfx4 Bfr[4];
    floatx4 S0 = zf, S1 = zf, S2 = zf, S3 = zf;
    float Lsnap = 0.f;
    float off = 0.f, s_lag = 1.f, dOff = 0.f;

    auto colsum_update = [&]() {
        halfx4 Bs = Bfr[0] + Bfr[1] + Bfr[2] + Bfr[3];
        floatx4 ds = MFMA16(Ao, Bs, zf);
        float cs = ds[0];
        unsigned bi = __float_as_uint(cs);
        int e = (int)((bi >> 23) & 0xff);
        s_lag = __uint_as_float((unsigned)(254 - e) << 23);
        dOff = (float)(e - 127) * LN2;
    };

    // independent MFMA K-slices + add tree (chain depth: 1 MFMA + 2 adds)
#define DMATVEC(D)                                               \
    {                                                            \
        _Pragma("unroll")                                        \
        for (int mt = 0; mt < 4; ++mt) {                         \
            floatx4 a0 = MFMA16(Afr[mt][0], Bfr[0], zf);         \
            floatx4 a1 = MFMA16(Afr[mt][1], Bfr[1], zf);         \
            floatx4 a2 = MFMA16(Afr[mt][2], Bfr[2], zf);         \
            floatx4 a3 = MFMA16(Afr[mt][3], Bfr[3], zf);         \
            D[mt] = (a0 + a1) + (a2 + a3);                       \
        }                                                        \
    }

    if (wid == 0) {
        // ---------------- forward ----------------
        #pragma unroll
        for (int mt = 0; mt < 4; ++mt) {
            floatx4 ia = reinterpret_cast<const floatx4*>(inita)[4 * mt + q];
            floatx4 l0 = reinterpret_cast<const floatx4*>(lgb)[4 * mt + q];
            #pragma unroll
            for (int r = 0; r < 4; ++r) U[mt][r] = __expf(ia[r] + l0[r]);
        }
        if (mym == 0) { S0 = U[0]; S1 = U[1]; S2 = U[2]; S3 = U[3]; Lsnap = 0.f; }
        #pragma unroll
        for (int kt = 0; kt < 4; ++kt)
            #pragma unroll
            for (int i = 0; i < 4; ++i) Bfr[kt][i] = (_Float16)U[kt][i];
        colsum_update();

        floatx4 RA[4], RB[4], RC[4], RD[4];
        {
            int r1 = 1 < T - 1 ? 1 : T - 1, r2 = 2 < T - 1 ? 2 : T - 1;
            int r3 = 3 < T - 1 ? 3 : T - 1, r4 = 4 < T - 1 ? 4 : T - 1;
            const floatx4* p1 = reinterpret_cast<const floatx4*>(lgb + (size_t)r1 * NC);
            const floatx4* p2 = reinterpret_cast<const floatx4*>(lgb + (size_t)r2 * NC);
            const floatx4* p3 = reinterpret_cast<const floatx4*>(lgb + (size_t)r3 * NC);
            const floatx4* p4 = reinterpret_cast<const floatx4*>(lgb + (size_t)r4 * NC);
            #pragma unroll
            for (int mt = 0; mt < 4; ++mt) {
                RA[mt] = p1[4 * mt + q]; RB[mt] = p2[4 * mt + q];
                RC[mt] = p3[4 * mt + q]; RD[mt] = p4[4 * mt + q];
            }
        }

        auto FSTEP = [&](floatx4* R, int tt) {
            floatx4 F[4];
            #pragma unroll
            for (int mt = 0; mt < 4; ++mt)
                #pragma unroll
                for (int r = 0; r < 4; ++r) F[mt][r] = __expf(R[mt][r]) * s_lag;
            off += dOff;
            int pf = tt + 4; pf = pf < T - 1 ? pf : T - 1;
            const floatx4* rp = reinterpret_cast<const floatx4*>(lgb + (size_t)pf * NC);
            #pragma unroll
            for (int mt = 0; mt < 4; ++mt) R[mt] = rp[4 * mt + q];
            floatx4 D[4];
            DMATVEC(D)
            #pragma unroll
            for (int mt = 0; mt < 4; ++mt)
                #pragma unroll
                for (int r = 0; r < 4; ++r) U[mt][r] = D[mt][r] * F[mt][r];
            if (tt == mym) { S0 = U[0]; S1 = U[1]; S2 = U[2]; S3 = U[3]; Lsnap = off; }
            #pragma unroll
            for (int kt = 0; kt < 4; ++kt)
                #pragma unroll
                for (int i = 0; i < 4; ++i) Bfr[kt][i] = (_Float16)U[kt][i];
            colsum_update();
        };

        int t = 1;
        for (; t + 3 <= maxm; t += 4) {
            FSTEP(RA, t); FSTEP(RB, t + 1); FSTEP(RC, t + 2); FSTEP(RD, t + 3);
        }
        if (t + 0 <= maxm) FSTEP(RA, t + 0);
        if (t + 1 <= maxm) FSTEP(RB, t + 1);
        if (t + 2 <= maxm) FSTEP(RC, t + 2);

        #pragma unroll
        for (int mt = 0; mt < 4; ++mt)
            #pragma unroll
            for (int r = 0; r < 4; ++r) {
                float sv = (mt == 0 ? S0[r] : mt == 1 ? S1[r] : mt == 2 ? S2[r] : S3[r]);
                Xf[16 * mt + 4 * q + r][col] = sv;
            }
        if (q == 0) Lshf[col] = Lsnap;
    } else {
        // ---------------- backward ----------------
        #pragma unroll
        for (int mt = 0; mt < 4; ++mt)
            #pragma unroll
            for (int r = 0; r < 4; ++r) U[mt][r] = 1.f;
        s_lag = 1.f; dOff = 0.f; off = 0.f;

        floatx4 RA[4], RB[4], RC[4], RD[4];
        {
            int r1 = maxlen - 1; r1 = r1 > 1 ? r1 : 1;
            int r2 = maxlen - 2; r2 = r2 > 1 ? r2 : 1;
            int r3 = maxlen - 3; r3 = r3 > 1 ? r3 : 1;
            int r4 = maxlen - 4; r4 = r4 > 1 ? r4 : 1;
            const floatx4* p1 = reinterpret_cast<const floatx4*>(lgb + (size_t)r1 * NC);
            const floatx4* p2 = reinterpret_cast<const floatx4*>(lgb + (size_t)r2 * NC);
            const floatx4* p3 = reinterpret_cast<const floatx4*>(lgb + (size_t)r3 * NC);
            const floatx4* p4 = reinterpret_cast<const floatx4*>(lgb + (size_t)r4 * NC);
            #pragma unroll
            for (int mt = 0; mt < 4; ++mt) {
                RA[mt] = p1[4 * mt + q]; RB[mt] = p2[4 * mt + q];
                RC[mt] = p3[4 * mt + q]; RD[mt] = p4[4 * mt + q];
            }
        }

        auto BSTEP = [&](floatx4* R, int tb) {
            if (tb == mylen - 1) {
                #pragma unroll
                for (int mt = 0; mt < 4; ++mt)
                    #pragma unroll
                    for (int r = 0; r < 4; ++r) U[mt][r] = 1.f;
                off = 0.f; s_lag = 1.f; dOff = 0.f;
            }
            floatx4 W[4];
            #pragma unroll
            for (int mt = 0; mt < 4; ++mt)
                #pragma unroll
                for (int r = 0; r < 4; ++r)
                    W[mt][r] = U[mt][r] * (__expf(R[mt][r]) * s_lag);
            off += dOff;
            int pf = tb - 4; pf = pf > 1 ? pf : 1;
            const floatx4* rp = reinterpret_cast<const floatx4*>(lgb + (size_t)pf * NC);
            #pragma unroll
            for (int mt = 0; mt < 4; ++mt) R[mt] = rp[4 * mt + q];
            #pragma unroll
            for (int kt = 0; kt < 4; ++kt)
                #pragma unroll
                for (int i = 0; i < 4; ++i) Bfr[kt][i] = (_Float16)W[kt][i];
            floatx4 D[4];
            DMATVEC(D)
            colsum_update();
            #pragma unroll
            for (int mt = 0; mt < 4; ++mt) U[mt] = D[mt];
            if (tb - 1 == mym) { S0 = U[0]; S1 = U[1]; S2 = U[2]; S3 = U[3]; Lsnap = off; }
        };

        int tb = maxlen - 1;
        for (; tb - 3 >= minm + 1; tb -= 4) {
            BSTEP(RA, tb); BSTEP(RB, tb - 1); BSTEP(RC, tb - 2); BSTEP(RD, tb - 3);
        }
        if (tb - 0 >= minm + 1) BSTEP(RA, tb - 0);
        if (tb - 1 >= minm + 1) BSTEP(RB, tb - 1);
        if (tb - 2 >= minm + 1) BSTEP(RC, tb - 2);

        #pragma unroll
        for (int mt = 0; mt < 4; ++mt)
            #pragma unroll
            for (int r = 0; r < 4; ++r) {
                float sv = (mt == 0 ? S0[r] : mt == 1 ? S1[r] : mt == 2 ? S2[r] : S3[r]);
                Xb[16 * mt + 4 * q + r][col] = sv;
            }
        if (q == 0) Lshb[col] = Lsnap;
    }

    __syncthreads();

    // ---- combine: logZ = Lf + Lb + log(sum_c Xf[c]*Xb[c]); out = logZ - gold
    if (tid < 16) {
        const int n = tid;
        float acc = 0.f;
        #pragma unroll 8
        for (int c = 0; c < 64; ++c) acc += Xf[c][n] * Xb[c][n];
        int s2 = perm[16 * g + n];
        out[s2] = Lshf[n] + Lshb[n] + __logf(acc) - gold[s2];
    }
}

extern "C" void kernel_launch(void* const* d_in, const int* in_sizes, int n_in,
                              void* d_out, int out_size, void* d_ws, size_t ws_size,
                              hipStream_t stream)
{
    const float* logits = (const float*)d_in[0];   // [N][T][C] f32
    const float* trans  = (const float*)d_in[1];   // [C][C]    f32
    const float* inita  = (const float*)d_in[2];   // [C]       f32
    const int*   lens   = (const int*)d_in[3];     // [N]       i32
    const int*   tags   = (const int*)d_in[4];     // [N][T]    i32
    float*       out    = (float*)d_out;           // [N]       f32

    const int N = 512, T = 1024;
    int*   perm = (int*)d_ws;
    float* gold = (float*)d_ws + 512;

    prep_kernel<<<N, 64, 0, stream>>>(logits, trans, inita, lens, tags, perm, gold, N, T);
    crf_mfma<<<N / 16, 128, 0, stream>>>(logits, trans, inita, lens, perm, gold, out, N, T);
}

// Round 19
// 131.019 us; speedup vs baseline: 2.1593x; 2.1593x over previous
//
#include <hip/hip_runtime.h>
#include <cstdint>
#include <cstddef>

#define NC 64
#define LN2 0.6931471805599453f

typedef _Float16 half2_t __attribute__((ext_vector_type(2)));
typedef unsigned int uint32x4 __attribute__((ext_vector_type(4)));

static __device__ __forceinline__ float dot2acc(uint32_t a, uint32_t b, float c) {
#if __has_builtin(__builtin_amdgcn_fdot2)
    return __builtin_amdgcn_fdot2(__builtin_bit_cast(half2_t, a),
                                  __builtin_bit_cast(half2_t, b), c, false);
#else
    half2_t ha = __builtin_bit_cast(half2_t, a), hb = __builtin_bit_cast(half2_t, b);
    return c + (float)ha[0] * (float)hb[0] + (float)ha[1] * (float)hb[1];
#endif
}

template <int CTRL>
static __device__ __forceinline__ float dppf(float x) {
    return __int_as_float(__builtin_amdgcn_update_dpp(
        0, __float_as_int(x), CTRL, 0xf, 0xf, true));
}
static __device__ __forceinline__ float wave_sum_bcast(float x) {
    x = x + dppf<0x111>(x);
    x = x + dppf<0x112>(x);
    x = x + dppf<0x114>(x);
    x = x + dppf<0x118>(x);
    x = x + dppf<0x142>(x);   // row_bcast15
    x = x + dppf<0x143>(x);   // row_bcast31
    return __int_as_float(__builtin_amdgcn_readlane(__float_as_int(x), 63));
}

// DPP ctrls: 0xB1 ^1 (quad), 0x4E ^2 (quad), 0x141 ^7 (half_mirror), 0x140 ^15 (mirror)

__global__ __launch_bounds__(128, 1)
void crf_nll_kernel(const float* __restrict__ logits,
                    const float* __restrict__ trans,
                    const float* __restrict__ init_alphas,
                    const int*  __restrict__ lengths,
                    const int*  __restrict__ tags,
                    float* __restrict__ out,
                    int N, int T)
{
    const int n = blockIdx.x;
    const int tid = threadIdx.x;
    const int wid = tid >> 6;          // wave 0: forward alpha; wave 1: backward beta
    const int lane = tid & 63;
    const float* lg = logits + (size_t)n * T * NC;
    const int len = lengths[n];        // in [2, T]
    const int Tm1 = T - 1;

    __shared__ __align__(16) uint32_t Etab[2][64 * 32]; // per-lane split-dot layout, f16x2
    __shared__ __align__(16) uint16_t st_pk[2][NC + 8]; // per-wave state exchange (f16)
    __shared__ __align__(16) float xchg[2][NC];
    __shared__ float Lsh[2], gsh[2];

    // ---- fill tables: lane i, word (j,k) holds E-row (i^D(j)), classes (8s+2k, 8s+2k+1)
    //      D(j) = (j&3)|((j&4)<<1)  in {0,1,2,3,8,9,10,11};  s(i) = (i&3)|((i>>1)&4)
    //      tab0 = exp(trans[row][c]) (forward); tab1 = exp(trans[c][row]) (backward, E^T)
    #pragma unroll
    for (int idx = tid; idx < 2 * 64 * 32; idx += 128) {
        int tab = idx >> 11, rem = idx & 2047;
        int i = rem >> 5, wrd = rem & 31;
        int j = wrd >> 2, k = wrd & 3;
        int D = (j & 3) | ((j & 4) << 1);
        int row = i ^ D;
        int s = (i & 3) | ((i >> 1) & 4);
        int c0 = 8 * s + 2 * k, c1 = c0 + 1;
        float x0 = tab == 0 ? trans[row * NC + c0] : trans[c0 * NC + row];
        float x1 = tab == 0 ? trans[row * NC + c1] : trans[c1 * NC + row];
        uint32_t lo = (uint32_t)__builtin_bit_cast(uint16_t, (_Float16)__expf(x0));
        uint32_t hi = (uint32_t)__builtin_bit_cast(uint16_t, (_Float16)__expf(x1));
        Etab[tab][i * 32 + wrd] = lo | (hi << 16);
    }
    __syncthreads();

    // ---- hoist this wave's 128B E block into 8 vec4 regs via inline asm
    uint32x4 e0, e1, e2, e3, e4, e5, e6, e7;
    {
        uint32_t e_addr = (uint32_t)(uintptr_t)&Etab[wid][0] + (uint32_t)(lane * 128);
        asm volatile(
            "ds_read_b128 %0, %8 offset:0\n\t"
            "ds_read_b128 %1, %8 offset:16\n\t"
            "ds_read_b128 %2, %8 offset:32\n\t"
            "ds_read_b128 %3, %8 offset:48\n\t"
            "ds_read_b128 %4, %8 offset:64\n\t"
            "ds_read_b128 %5, %8 offset:80\n\t"
            "ds_read_b128 %6, %8 offset:96\n\t"
            "ds_read_b128 %7, %8 offset:112\n\t"
            "s_waitcnt lgkmcnt(0)"
            : "=&v"(e0), "=&v"(e1), "=&v"(e2), "=&v"(e3),
              "=&v"(e4), "=&v"(e5), "=&v"(e6), "=&v"(e7)
            : "v"(e_addr)
            : "memory");
        __builtin_amdgcn_sched_barrier(0);
    }

    const int m  = (len - 1) >> 1;     // forward does m steps
    const int nb = len - 1 - m;        // backward does nb >= 1 steps

    uint16_t* my_pk = st_pk[wid];
    const int s_lane = (lane & 3) | ((lane >> 1) & 4);
    const uint32x4* wchunk = reinterpret_cast<const uint32x4*>(my_pk + 8 * s_lane);

    float L = 0.f, vcur = 1.0f, s_cur = 1.0f, dL = 0.0f;

    // split-dot + DPP-tree: returns full dot for row `lane`
    auto dotE = [&]() -> float {
        const uint32x4 w = wchunk[0];              // ONE ds_read_b128 (8-way broadcast)
        float p0, p1, p2, p3, p4, p5, p6, p7;
        p0 = dot2acc(e0.x, w.x, dot2acc(e0.y, w.y, dot2acc(e0.z, w.z, dot2acc(e0.w, w.w, 0.f))));
        p1 = dot2acc(e1.x, w.x, dot2acc(e1.y, w.y, dot2acc(e1.z, w.z, dot2acc(e1.w, w.w, 0.f))));
        p2 = dot2acc(e2.x, w.x, dot2acc(e2.y, w.y, dot2acc(e2.z, w.z, dot2acc(e2.w, w.w, 0.f))));
        p3 = dot2acc(e3.x, w.x, dot2acc(e3.y, w.y, dot2acc(e3.z, w.z, dot2acc(e3.w, w.w, 0.f))));
        p4 = dot2acc(e4.x, w.x, dot2acc(e4.y, w.y, dot2acc(e4.z, w.z, dot2acc(e4.w, w.w, 0.f))));
        p5 = dot2acc(e5.x, w.x, dot2acc(e5.y, w.y, dot2acc(e5.z, w.z, dot2acc(e5.w, w.w, 0.f))));
        p6 = dot2acc(e6.x, w.x, dot2acc(e6.y, w.y, dot2acc(e6.z, w.z, dot2acc(e6.w, w.w, 0.f))));
        p7 = dot2acc(e7.x, w.x, dot2acc(e7.y, w.y, dot2acc(e7.z, w.z, dot2acc(e7.w, w.w, 0.f))));
        // butterfly reduce over lanes: p_D holds partial of row lane^D, D={0,1,2,3,8,9,10,11}
        float q0  = p0 + dppf<0xB1>(p1);           // ^1: rows lane, partner covers other classes
        float q2  = p2 + dppf<0xB1>(p3);
        float q8  = p4 + dppf<0xB1>(p5);
        float q10 = p6 + dppf<0xB1>(p7);
        float r0 = q0 + dppf<0x4E>(q2);            // ^2
        float r8 = q8 + dppf<0x4E>(q10);
        float t8 = dppf<0x141>(r8);                // ^7
        return r0 + dppf<0x140>(t8);               // ^15 ∘ ^7 = ^8
    };

    if (wid == 0) {
        // ---------------- forward: alpha_0 .. alpha_m ----------------
        float a0 = init_alphas[lane] + lg[lane];
        L = __int_as_float(__builtin_amdgcn_readfirstlane(__float_as_int(a0))) + 8.f * LN2;
        vcur = __expf(a0 - L);
        my_pk[lane] = __builtin_bit_cast(uint16_t, (_Float16)vcur);

        auto fstep = [&](float raw) {
            float fs = __expf(raw) * s_cur;
            L += dL;
            float v = fs * dotE();
            vcur = v;
            my_pk[lane] = __builtin_bit_cast(uint16_t, (_Float16)v);
            unsigned bits = (unsigned)__builtin_amdgcn_readfirstlane((int)__float_as_uint(v));
            int e = (int)((bits >> 23) & 0xFF);
            s_cur = __uint_as_float((unsigned)(246 - e) << 23);   // 2^(119-e)
            dL    = (float)(e - 119) * LN2;
        };

        float r0 = lg[NC * (1 < Tm1 ? 1 : Tm1) + lane];
        float r1 = lg[NC * (2 < Tm1 ? 2 : Tm1) + lane];
        float r2 = lg[NC * (3 < Tm1 ? 3 : Tm1) + lane];
        float r3 = lg[NC * (4 < Tm1 ? 4 : Tm1) + lane];
        float r4 = lg[NC * (5 < Tm1 ? 5 : Tm1) + lane];
        float r5 = lg[NC * (6 < Tm1 ? 6 : Tm1) + lane];
        float r6 = lg[NC * (7 < Tm1 ? 7 : Tm1) + lane];
        float r7 = lg[NC * (8 < Tm1 ? 8 : Tm1) + lane];

        int t = 1;
        for (; t + 8 <= m + 1; t += 8) {
            int p;
            fstep(r0); p = t +  8; p = p < Tm1 ? p : Tm1; r0 = lg[NC * p + lane];
            fstep(r1); p = t +  9; p = p < Tm1 ? p : Tm1; r1 = lg[NC * p + lane];
            fstep(r2); p = t + 10; p = p < Tm1 ? p : Tm1; r2 = lg[NC * p + lane];
            fstep(r3); p = t + 11; p = p < Tm1 ? p : Tm1; r3 = lg[NC * p + lane];
            fstep(r4); p = t + 12; p = p < Tm1 ? p : Tm1; r4 = lg[NC * p + lane];
            fstep(r5); p = t + 13; p = p < Tm1 ? p : Tm1; r5 = lg[NC * p + lane];
            fstep(r6); p = t + 14; p = p < Tm1 ? p : Tm1; r6 = lg[NC * p + lane];
            fstep(r7); p = t + 15; p = p < Tm1 ? p : Tm1; r7 = lg[NC * p + lane];
        }
        if (t + 0 <= m) fstep(r0);
        if (t + 1 <= m) fstep(r1);
        if (t + 2 <= m) fstep(r2);
        if (t + 3 <= m) fstep(r3);
        if (t + 4 <= m) fstep(r4);
        if (t + 5 <= m) fstep(r5);
        if (t + 6 <= m) fstep(r6);
    } else {
        // ---------------- backward: beta_{len-1}=0 down to beta_m ----------------
        auto bstep = [&](float raw) {
            float p = __expf(raw) * s_cur * vcur;   // own-lane product, then E^T gather
            L += dL;
            my_pk[lane] = __builtin_bit_cast(uint16_t, (_Float16)p);
            float u = dotE();
            vcur = u;
            unsigned bits = (unsigned)__builtin_amdgcn_readfirstlane((int)__float_as_uint(u));
            int e = (int)((bits >> 23) & 0xFF);
            s_cur = __uint_as_float((unsigned)(246 - e) << 23);   // 2^(119-e)
            dL    = (float)(e - 119) * LN2;
        };

        int p0i;
        p0i = len - 1; p0i = p0i > 1 ? p0i : 1; float r0 = lg[NC * p0i + lane];
        p0i = len - 2; p0i = p0i > 1 ? p0i : 1; float r1 = lg[NC * p0i + lane];
        p0i = len - 3; p0i = p0i > 1 ? p0i : 1; float r2 = lg[NC * p0i + lane];
        p0i = len - 4; p0i = p0i > 1 ? p0i : 1; float r3 = lg[NC * p0i + lane];
        p0i = len - 5; p0i = p0i > 1 ? p0i : 1; float r4 = lg[NC * p0i + lane];
        p0i = len - 6; p0i = p0i > 1 ? p0i : 1; float r5 = lg[NC * p0i + lane];
        p0i = len - 7; p0i = p0i > 1 ? p0i : 1; float r6 = lg[NC * p0i + lane];
        p0i = len - 8; p0i = p0i > 1 ? p0i : 1; float r7 = lg[NC * p0i + lane];

        int k = 0;
        for (; k + 8 <= nb; k += 8) {
            int p;
            bstep(r0); p = len - 1 - (k +  8); p = p > 1 ? p : 1; r0 = lg[NC * p + lane];
            bstep(r1); p = len - 1 - (k +  9); p = p > 1 ? p : 1; r1 = lg[NC * p + lane];
            bstep(r2); p = len - 1 - (k + 10); p = p > 1 ? p : 1; r2 = lg[NC * p + lane];
            bstep(r3); p = len - 1 - (k + 11); p = p > 1 ? p : 1; r3 = lg[NC * p + lane];
            bstep(r4); p = len - 1 - (k + 12); p = p > 1 ? p : 1; r4 = lg[NC * p + lane];
            bstep(r5); p = len - 1 - (k + 13); p = p > 1 ? p : 1; r5 = lg[NC * p + lane];
            bstep(r6); p = len - 1 - (k + 14); p = p > 1 ? p : 1; r6 = lg[NC * p + lane];
            bstep(r7); p = len - 1 - (k + 15); p = p > 1 ? p : 1; r7 = lg[NC * p + lane];
        }
        if (k + 0 < nb) bstep(r0);
        if (k + 1 < nb) bstep(r1);
        if (k + 2 < nb) bstep(r2);
        if (k + 3 < nb) bstep(r3);
        if (k + 4 < nb) bstep(r4);
        if (k + 5 < nb) bstep(r5);
        if (k + 6 < nb) bstep(r6);
    }

    // ---- publish per-wave results
    xchg[wid][lane] = vcur;
    if (lane == 0) Lsh[wid] = L;

    // ---- gold score: both waves cooperate (128-thread stride)
    const int* tg = tags + (size_t)n * T;
    float g = 0.f;
    for (int tt = 1 + tid; tt < len; tt += 128) {
        const int cur = tg[tt];
        const int prv = tg[tt - 1];
        g += trans[cur * NC + prv] + lg[tt * NC + cur];
    }
    g = wave_sum_bcast(g);
    if (lane == 0) gsh[wid] = g;

    __syncthreads();

    if (wid == 0) {
        float prod = xchg[0][lane] * xchg[1][lane];
        float ssum = wave_sum_bcast(prod);
        if (lane == 0) {
            float logZ = Lsh[0] + Lsh[1] + __logf(ssum);
            int t0v = tg[0];
            float gold = init_alphas[t0v] + lg[t0v] + gsh[0] + gsh[1];
            out[n] = logZ - gold;
        }
    }
}

extern "C" void kernel_launch(void* const* d_in, const int* in_sizes, int n_in,
                              void* d_out, int out_size, void* d_ws, size_t ws_size,
                              hipStream_t stream)
{
    const float* logits = (const float*)d_in[0];   // [N][T][C] f32
    const float* trans  = (const float*)d_in[1];   // [C][C]    f32
    const float* inita  = (const float*)d_in[2];   // [C]       f32
    const int*   lens   = (const int*)d_in[3];     // [N]       i32
    const int*   tags   = (const int*)d_in[4];     // [N][T]    i32
    float*       out    = (float*)d_out;           // [N]       f32

    const int N = 512, T = 1024;
    crf_nll_kernel<<<N, 128, 0, stream>>>(logits, trans, inita, lens, tags, out, N, T);
}